// Round 7
// baseline (1486.401 us; speedup 1.0000x reference)
//
#include <hip/hip_runtime.h>

typedef __attribute__((ext_vector_type(8))) short bfrag;   // 8 bf16 (4 VGPRs)
typedef __attribute__((ext_vector_type(4))) float f32x4;   // MFMA C/D
typedef __attribute__((ext_vector_type(4))) int i32x4;     // 16B moves

#define NT 512      // seq len
#define NB 64       // batch
#define KD 512      // D == H == 512
#define NG 2048     // 4*H gate rows
#define GB 4        // batch blocks (16 batch each)
#define GH 16       // h-slices (32 dims each)

#define YS_SZ (NT * NB * KD)          // 16777216
#define HT_OFF YS_SZ
#define CT_OFF (YS_SZ + NB * KD)

// mailbox: [2 parity][GB blocks][256 pairs][16 batch] of u64 {tag32 | bf16x2}
#define MB_BLK_WORDS 4096
#define MB_PAR_WORDS (GB * MB_BLK_WORDS)
#define MB_BYTES (2 * MB_PAR_WORDS * 8)   // 262144

__device__ __forceinline__ unsigned short f2bf(float f) {
  unsigned u = __float_as_uint(f);
  u += 0x7fffu + ((u >> 16) & 1u);
  return (unsigned short)(u >> 16);
}
__device__ __forceinline__ float bf2f(unsigned short h) {
  return __uint_as_float(((unsigned)h) << 16);
}
__device__ __forceinline__ float sigm(float v) { return 1.f / (1.f + __expf(-v)); }
__device__ __forceinline__ float tanh_f(float v) { return 1.f - 2.f / (__expf(2.f * v) + 1.f); }

// ---------------- fp32 -> bf16 convert (vectorized) ----------------
__global__ __launch_bounds__(256) void cvt_bf16(const float* __restrict__ src,
                                                unsigned short* __restrict__ dst, int n8) {
  int i = blockIdx.x * 256 + threadIdx.x;
  if (i >= n8) return;
  const float4 a = *(const float4*)(src + (size_t)i * 8);
  const float4 b = *(const float4*)(src + (size_t)i * 8 + 4);
  i32x4 v;
  v.x = (int)(f2bf(a.x) | ((unsigned)f2bf(a.y) << 16));
  v.y = (int)(f2bf(a.z) | ((unsigned)f2bf(a.w) << 16));
  v.z = (int)(f2bf(b.x) | ((unsigned)f2bf(b.y) << 16));
  v.w = (int)(f2bf(b.z) | ((unsigned)f2bf(b.w) << 16));
  *(i32x4*)(dst + (size_t)i * 8) = v;
}

// ---------------- Phase A: x_proj[t][n][b] = sum_k W_ih[n][k]*x[t][b][k] + b_ih[n] --------
template <int XP32>
__global__ __launch_bounds__(256) void xproj_gemm(const unsigned short* __restrict__ Wb,
                                                  const unsigned short* __restrict__ Xb,
                                                  const float* __restrict__ bias,
                                                  void* __restrict__ XPv) {
  __shared__ unsigned short Wt[64 * 40];
  __shared__ unsigned short Xt[64 * 40];
  const int tid = threadIdx.x;
  const int lane = tid & 63, wid = tid >> 6;
  const int g = lane >> 4, cc = lane & 15;
  const int n0 = blockIdx.x * 64;
  const int t = blockIdx.y;
  const size_t m0 = (size_t)t * 64;
  const int srow = tid >> 2, schunk = (tid & 3) * 8;

  f32x4 acc[4] = {};
  for (int kb = 0; kb < KD; kb += 32) {
    __syncthreads();
    *(i32x4*)&Wt[srow * 40 + schunk] = *(const i32x4*)(Wb + (size_t)(n0 + srow) * KD + kb + schunk);
    *(i32x4*)&Xt[srow * 40 + schunk] = *(const i32x4*)(Xb + (m0 + srow) * KD + kb + schunk);
    __syncthreads();
    bfrag af = *(const bfrag*)&Wt[(wid * 16 + cc) * 40 + g * 8];
#pragma unroll
    for (int mt = 0; mt < 4; ++mt) {
      bfrag bf = *(const bfrag*)&Xt[(mt * 16 + cc) * 40 + g * 8];
      acc[mt] = __builtin_amdgcn_mfma_f32_16x16x32_bf16(af, bf, acc[mt], 0, 0, 0);
    }
  }
  const int nl = wid * 16 + g * 4;
  float bi[4];
#pragma unroll
  for (int r = 0; r < 4; ++r) bi[r] = bias[n0 + nl + r];
#pragma unroll
  for (int mt = 0; mt < 4; ++mt) {
#pragma unroll
    for (int r = 0; r < 4; ++r) {
      float v = acc[mt][r] + bi[r];
      size_t idx = ((size_t)t * NG + n0 + nl + r) * 64 + mt * 16 + cc;
      if (XP32) ((float*)XPv)[idx] = v;
      else ((unsigned short*)XPv)[idx] = f2bf(v);
    }
  }
}

// ---------------- Phase B: persistent recurrence, tagged-data mailbox ----------------
// grid = 64: blk = bid>>4 (16 batches), slice = bid&15 (32 dims).
// R6 transport (single-hop tagged words, exact-tag accept, parity-2, no fences) plus:
//  - poll loads PRE-ISSUED at iteration bottom; xp loads asm-issued AFTER them;
//    round 1 waits vmcnt(8) (all 16 polls complete in-order, xp still flying),
//    retry rounds vmcnt(0); xp drained by vmcnt(0) after MFMA (hidden).
//  - ys/hT/cT stored directly from registers (no LDS transpose, one barrier/step).
template <int XP32>
__global__ __launch_bounds__(256, 1) void lstm_rec(const unsigned short* __restrict__ Whh,
                                                   const void* __restrict__ XPv,
                                                   const float* __restrict__ bhh,
                                                   const float* __restrict__ h0,
                                                   const float* __restrict__ c0,
                                                   unsigned long long* __restrict__ mbox,
                                                   float* __restrict__ out) {
  __shared__ unsigned short hl[16 * 512];  // h block, XOR-swizzled rows (16KB)

  const int tid = threadIdx.x;
  const int lane = tid & 63, wid = tid >> 6;
  const int g = lane >> 4, cc = lane & 15;
  const int blk = blockIdx.x >> 4, slice = blockIdx.x & 15;
  const int b0 = blk * 16, d0 = slice * 32;

  // ---- publish our slice of h0 (tag=1) into parity-0 mailbox, ASAP (1 word/thread)
  {
    const int lp = tid >> 4, b = tid & 15;  // local pair, batch row
    const int d = d0 + lp * 2;
    const float* hp = h0 + (size_t)(b0 + b) * KD + d;
    unsigned d32 = (unsigned)f2bf(hp[0]) | ((unsigned)f2bf(hp[1]) << 16);
    __hip_atomic_store(mbox + (size_t)blk * MB_BLK_WORDS + ((d0 >> 1) + lp) * 16 + b,
                       (1ull << 32) | (unsigned long long)d32, __ATOMIC_RELAXED,
                       __HIP_MEMORY_SCOPE_AGENT);
  }

  // ---- preload W_hh slice into registers: 2 tiles x 16 k-steps of bf16x8
  bfrag w[2][16];
#pragma unroll
  for (int j = 0; j < 2; ++j) {
    const int tt = wid * 2 + j;
    const int r = tt * 16 + cc;  // A-operand row = lane&15
    const size_t n = (size_t)(r & 3) * KD + d0 + (r >> 2);
#pragma unroll
    for (int ks = 0; ks < 16; ++ks)
      w[j][ks] = *(const bfrag*)(Whh + n * KD + ks * 32 + g * 8);
  }
  float bh[2][4], creg[2];
#pragma unroll
  for (int j = 0; j < 2; ++j) {
    const int d = d0 + (wid * 2 + j) * 4 + g;
#pragma unroll
    for (int r = 0; r < 4; ++r) bh[j][r] = bhh[r * KD + d];
    creg[j] = c0[(b0 + cc) * KD + d];
  }

  unsigned long long q0, q1, q2, q3, q4, q5, q6, q7, q8, q9, q10, q11, q12, q13, q14, q15;

#define PISSUE(MB, r)                                                       \
  asm volatile("global_load_dwordx2 %0, %1, %2 sc1"                         \
               : "=v"(q##r)                                                 \
               : "v"((unsigned)(tid * 8 + r * 2048)), "s"(MB) : "memory")
#define PISSUE_ALL(MB)                                                      \
  do {                                                                      \
    PISSUE(MB, 0); PISSUE(MB, 1); PISSUE(MB, 2); PISSUE(MB, 3);             \
    PISSUE(MB, 4); PISSUE(MB, 5); PISSUE(MB, 6); PISSUE(MB, 7);             \
    PISSUE(MB, 8); PISSUE(MB, 9); PISSUE(MB, 10); PISSUE(MB, 11);           \
    PISSUE(MB, 12); PISSUE(MB, 13); PISSUE(MB, 14); PISSUE(MB, 15);         \
  } while (0)
#define PCHK_ALL(okv, tg)                                                   \
  do {                                                                      \
    okv = 1u;                                                               \
    okv &= ((unsigned)(q0 >> 32) == (tg)); okv &= ((unsigned)(q1 >> 32) == (tg));   \
    okv &= ((unsigned)(q2 >> 32) == (tg)); okv &= ((unsigned)(q3 >> 32) == (tg));   \
    okv &= ((unsigned)(q4 >> 32) == (tg)); okv &= ((unsigned)(q5 >> 32) == (tg));   \
    okv &= ((unsigned)(q6 >> 32) == (tg)); okv &= ((unsigned)(q7 >> 32) == (tg));   \
    okv &= ((unsigned)(q8 >> 32) == (tg)); okv &= ((unsigned)(q9 >> 32) == (tg));   \
    okv &= ((unsigned)(q10 >> 32) == (tg)); okv &= ((unsigned)(q11 >> 32) == (tg)); \
    okv &= ((unsigned)(q12 >> 32) == (tg)); okv &= ((unsigned)(q13 >> 32) == (tg)); \
    okv &= ((unsigned)(q14 >> 32) == (tg)); okv &= ((unsigned)(q15 >> 32) == (tg)); \
  } while (0)

  // pre-issue polls for t=0 (parity 0)
  {
    const unsigned long long* nb = mbox + (size_t)blk * MB_BLK_WORDS;
    PISSUE_ALL(nb);
  }

  for (int t = 0; t < NT; ++t) {
    // ---- xp loads: asm-issued AFTER the pre-issued polls (8 newest vmem ops)
    unsigned xpr[2][4];
#pragma unroll
    for (int j = 0; j < 2; ++j) {
      const int d = d0 + (wid * 2 + j) * 4 + g;
#pragma unroll
      for (int r = 0; r < 4; ++r) {
        const size_t idx = ((size_t)t * NG + r * KD + d) * 64 + b0 + cc;
        if constexpr (XP32) {
          const float* p = (const float*)XPv + idx;
          asm volatile("global_load_dword %0, %1, off" : "=v"(xpr[j][r]) : "v"(p) : "memory");
        } else {
          const unsigned short* p = (const unsigned short*)XPv + idx;
          asm volatile("global_load_ushort %0, %1, off" : "=v"(xpr[j][r]) : "v"(p) : "memory");
        }
      }
    }
    // ---- poll: round 1 waits the 16 pre-issued polls only (in-order counter)
    const unsigned long long* mbr =
        mbox + (size_t)(t & 1) * MB_PAR_WORDS + (size_t)blk * MB_BLK_WORDS;
    const unsigned tg = (unsigned)(t + 1);
    asm volatile("s_waitcnt vmcnt(8)" ::: "memory");
    __builtin_amdgcn_sched_barrier(0);
    unsigned ok;
    PCHK_ALL(ok, tg);
    while (!__all(ok)) {
      PISSUE_ALL(mbr);
      asm volatile("s_waitcnt vmcnt(0)" ::: "memory");
      __builtin_amdgcn_sched_barrier(0);
      PCHK_ALL(ok, tg);
    }
    // unpack into swizzled LDS: word (r*256+tid) = pair p = r*16+(tid>>4), batch b = tid&15
    {
      const int b = tid & 15, pq = tid >> 4;
      const int bb = b * 1024, bx = (b & 7) << 4;
#define PUNP(r) \
  *(unsigned*)((char*)hl + bb + (((r * 16 + pq) * 4) ^ bx)) = (unsigned)q##r;
      PUNP(0) PUNP(1) PUNP(2) PUNP(3) PUNP(4) PUNP(5) PUNP(6) PUNP(7)
      PUNP(8) PUNP(9) PUNP(10) PUNP(11) PUNP(12) PUNP(13) PUNP(14) PUNP(15)
#undef PUNP
    }
    __syncthreads();
    // gates = W_slice @ h^T  (4 accumulators: chains of 8)
    f32x4 p00 = {0.f, 0.f, 0.f, 0.f}, p01 = {0.f, 0.f, 0.f, 0.f};
    f32x4 p10 = {0.f, 0.f, 0.f, 0.f}, p11 = {0.f, 0.f, 0.f, 0.f};
#pragma unroll
    for (int ks = 0; ks < 8; ++ks) {
      const int off = ks * 64 + g * 16;
      bfrag hb = *(const bfrag*)((const char*)hl + cc * 1024 + (off ^ ((cc & 7) << 4)));
      p00 = __builtin_amdgcn_mfma_f32_16x16x32_bf16(w[0][ks], hb, p00, 0, 0, 0);
      p10 = __builtin_amdgcn_mfma_f32_16x16x32_bf16(w[1][ks], hb, p10, 0, 0, 0);
    }
#pragma unroll
    for (int ks = 8; ks < 16; ++ks) {
      const int off = ks * 64 + g * 16;
      bfrag hb = *(const bfrag*)((const char*)hl + cc * 1024 + (off ^ ((cc & 7) << 4)));
      p01 = __builtin_amdgcn_mfma_f32_16x16x32_bf16(w[0][ks], hb, p01, 0, 0, 0);
      p11 = __builtin_amdgcn_mfma_f32_16x16x32_bf16(w[1][ks], hb, p11, 0, 0, 0);
    }
    const f32x4 acc0 = p00 + p01, acc1 = p10 + p11;
    // ---- xp drain (issued ~1 round + MFMA ago; usually complete) + pointwise
    asm volatile("s_waitcnt vmcnt(0)" ::: "memory");
    __builtin_amdgcn_sched_barrier(0);
    float hnv[2];
#pragma unroll
    for (int j = 0; j < 2; ++j) {
      const f32x4 a = j ? acc1 : acc0;
      float x0, x1, x2, x3;
      if constexpr (XP32) {
        x0 = __uint_as_float(xpr[j][0]); x1 = __uint_as_float(xpr[j][1]);
        x2 = __uint_as_float(xpr[j][2]); x3 = __uint_as_float(xpr[j][3]);
      } else {
        x0 = bf2f((unsigned short)xpr[j][0]); x1 = bf2f((unsigned short)xpr[j][1]);
        x2 = bf2f((unsigned short)xpr[j][2]); x3 = bf2f((unsigned short)xpr[j][3]);
      }
      float gi = a[0] + x0 + bh[j][0];
      float gf = a[1] + x1 + bh[j][1];
      float gg = a[2] + x2 + bh[j][2];
      float go = a[3] + x3 + bh[j][3];
      float cn = sigm(gf) * creg[j] + sigm(gi) * tanh_f(gg);
      creg[j] = cn;
      hnv[j] = sigm(go) * tanh_f(cn);
    }
    // ---- single-hop publish: pair dims via shfl, store (tag|bf16x2) words NOW; no drain
    {
      unsigned long long* mbw =
          mbox + (size_t)((t + 1) & 1) * MB_PAR_WORDS + (size_t)blk * MB_BLK_WORDS;
      const unsigned long long tagn = (unsigned long long)(unsigned)(t + 2) << 32;
      const float o0 = __shfl_xor(hnv[0], 16);
      const float o1 = __shfl_xor(hnv[1], 16);
      if (!(g & 1)) {
        const unsigned w0 = (unsigned)f2bf(hnv[0]) | ((unsigned)f2bf(o0) << 16);
        const unsigned w1 = (unsigned)f2bf(hnv[1]) | ((unsigned)f2bf(o1) << 16);
        const int p0 = (d0 >> 1) + wid * 4 + (g >> 1);
        const int p1 = p0 + 2;
        __hip_atomic_store(mbw + p0 * 16 + cc, tagn | (unsigned long long)w0,
                           __ATOMIC_RELAXED, __HIP_MEMORY_SCOPE_AGENT);
        __hip_atomic_store(mbw + p1 * 16 + cc, tagn | (unsigned long long)w1,
                           __ATOMIC_RELAXED, __HIP_MEMORY_SCOPE_AGENT);
      }
    }
    // ---- direct output stores from registers (fire-and-forget)
    {
      float* yb = out + (size_t)t * NB * KD + (size_t)(b0 + cc) * KD + d0 + wid * 8 + g;
      yb[0] = hnv[0];
      yb[4] = hnv[1];
      if (t == NT - 1) {
        float* hb = out + HT_OFF + (size_t)(b0 + cc) * KD + d0 + wid * 8 + g;
        hb[0] = hnv[0];
        hb[4] = hnv[1];
        float* cb = out + CT_OFF + (size_t)(b0 + cc) * KD + d0 + wid * 8 + g;
        cb[0] = creg[0];
        cb[4] = creg[1];
      }
    }
    // ---- pre-issue next step's polls (parity (t+1)&1)
    {
      const unsigned long long* nb =
          mbox + (size_t)((t + 1) & 1) * MB_PAR_WORDS + (size_t)blk * MB_BLK_WORDS;
      PISSUE_ALL(nb);
    }
  }
#undef PISSUE
#undef PISSUE_ALL
#undef PCHK_ALL
}

extern "C" void kernel_launch(void* const* d_in, const int* in_sizes, int n_in,
                              void* d_out, int out_size, void* d_ws, size_t ws_size,
                              hipStream_t stream) {
  const float* x = (const float*)d_in[0];
  const float* h0 = (const float*)d_in[1];
  const float* c0 = (const float*)d_in[2];
  const float* Wih = (const float*)d_in[3];
  const float* Whh = (const float*)d_in[4];
  const float* bih = (const float*)d_in[5];
  const float* bhh = (const float*)d_in[6];
  float* out = (float*)d_out;
  char* ws = (char*)d_ws;

  unsigned long long* mbox = (unsigned long long*)ws;                      // 256KB
  unsigned short* WhhB = (unsigned short*)(ws + MB_BYTES);                 // 2MB
  unsigned short* WihB = (unsigned short*)(ws + MB_BYTES + 2097152);       // 2MB
  unsigned short* XB = (unsigned short*)(ws + MB_BYTES + 2 * 2097152);     // 32MB
  const size_t xp_off = MB_BYTES + 2ull * 2097152 + 33554432;
  void* XP = (void*)(ws + xp_off);
  const bool xp32 = ws_size >= xp_off + (size_t)NT * NG * 64 * 4;

  hipMemsetAsync(ws, 0, MB_BYTES, stream);  // reset mailbox tags (poison/replay safe)

  const int nx8 = NT * NB * KD / 8;
  const int nw8 = NG * KD / 8;
  cvt_bf16<<<dim3(nx8 / 256), 256, 0, stream>>>(x, XB, nx8);
  cvt_bf16<<<dim3(nw8 / 256), 256, 0, stream>>>(Wih, WihB, nw8);
  cvt_bf16<<<dim3(nw8 / 256), 256, 0, stream>>>(Whh, WhhB, nw8);

  if (xp32) {
    xproj_gemm<1><<<dim3(NG / 64, NT), 256, 0, stream>>>(WihB, XB, bih, XP);
    lstm_rec<1><<<dim3(GB * GH), 256, 0, stream>>>(WhhB, XP, bhh, h0, c0, mbox, out);
  } else {
    xproj_gemm<0><<<dim3(NG / 64, NT), 256, 0, stream>>>(WihB, XB, bih, XP);
    lstm_rec<0><<<dim3(GB * GH), 256, 0, stream>>>(WhhB, XP, bhh, h0, c0, mbox, out);
  }
}

// Round 8
// 1461.401 us; speedup vs baseline: 1.0171x; 1.0171x over previous
//
#include <hip/hip_runtime.h>

typedef __attribute__((ext_vector_type(8))) short bfrag;   // 8 bf16 (4 VGPRs)
typedef __attribute__((ext_vector_type(4))) float f32x4;   // MFMA C/D
typedef __attribute__((ext_vector_type(4))) int i32x4;     // 16B moves

#define NT 512      // seq len
#define NB 64       // batch
#define KD 512      // D == H == 512
#define NG 2048     // 4*H gate rows
#define GB 4        // batch blocks (16 batch each)
#define GH 16       // h-slices (32 dims each)

#define YS_SZ (NT * NB * KD)          // 16777216
#define HT_OFF YS_SZ
#define CT_OFF (YS_SZ + NB * KD)

// mailbox: [2 parity][GB blocks][256 pairs][16 batch] of u64 {tag32 | bf16x2}
#define MB_BLK_WORDS 4096
#define MB_PAR_WORDS (GB * MB_BLK_WORDS)
#define MB_BYTES (2 * MB_PAR_WORDS * 8)   // 262144

__device__ __forceinline__ unsigned short f2bf(float f) {
  unsigned u = __float_as_uint(f);
  u += 0x7fffu + ((u >> 16) & 1u);
  return (unsigned short)(u >> 16);
}
__device__ __forceinline__ float bf2f(unsigned short h) {
  return __uint_as_float(((unsigned)h) << 16);
}
__device__ __forceinline__ float sigm(float v) { return 1.f / (1.f + __expf(-v)); }
__device__ __forceinline__ float tanh_f(float v) { return 1.f - 2.f / (__expf(2.f * v) + 1.f); }

// ---------------- fp32 -> bf16 convert (vectorized) ----------------
__global__ __launch_bounds__(256) void cvt_bf16(const float* __restrict__ src,
                                                unsigned short* __restrict__ dst, int n8) {
  int i = blockIdx.x * 256 + threadIdx.x;
  if (i >= n8) return;
  const float4 a = *(const float4*)(src + (size_t)i * 8);
  const float4 b = *(const float4*)(src + (size_t)i * 8 + 4);
  i32x4 v;
  v.x = (int)(f2bf(a.x) | ((unsigned)f2bf(a.y) << 16));
  v.y = (int)(f2bf(a.z) | ((unsigned)f2bf(a.w) << 16));
  v.z = (int)(f2bf(b.x) | ((unsigned)f2bf(b.y) << 16));
  v.w = (int)(f2bf(b.z) | ((unsigned)f2bf(b.w) << 16));
  *(i32x4*)(dst + (size_t)i * 8) = v;
}

// ---------------- Phase A: x_proj[t][n][b] = sum_k W_ih[n][k]*x[t][b][k] + b_ih[n] --------
template <int XP32>
__global__ __launch_bounds__(256) void xproj_gemm(const unsigned short* __restrict__ Wb,
                                                  const unsigned short* __restrict__ Xb,
                                                  const float* __restrict__ bias,
                                                  void* __restrict__ XPv) {
  __shared__ unsigned short Wt[64 * 40];
  __shared__ unsigned short Xt[64 * 40];
  const int tid = threadIdx.x;
  const int lane = tid & 63, wid = tid >> 6;
  const int g = lane >> 4, cc = lane & 15;
  const int n0 = blockIdx.x * 64;
  const int t = blockIdx.y;
  const size_t m0 = (size_t)t * 64;
  const int srow = tid >> 2, schunk = (tid & 3) * 8;

  f32x4 acc[4] = {};
  for (int kb = 0; kb < KD; kb += 32) {
    __syncthreads();
    *(i32x4*)&Wt[srow * 40 + schunk] = *(const i32x4*)(Wb + (size_t)(n0 + srow) * KD + kb + schunk);
    *(i32x4*)&Xt[srow * 40 + schunk] = *(const i32x4*)(Xb + (m0 + srow) * KD + kb + schunk);
    __syncthreads();
    bfrag af = *(const bfrag*)&Wt[(wid * 16 + cc) * 40 + g * 8];
#pragma unroll
    for (int mt = 0; mt < 4; ++mt) {
      bfrag bf = *(const bfrag*)&Xt[(mt * 16 + cc) * 40 + g * 8];
      acc[mt] = __builtin_amdgcn_mfma_f32_16x16x32_bf16(af, bf, acc[mt], 0, 0, 0);
    }
  }
  const int nl = wid * 16 + g * 4;
  float bi[4];
#pragma unroll
  for (int r = 0; r < 4; ++r) bi[r] = bias[n0 + nl + r];
#pragma unroll
  for (int mt = 0; mt < 4; ++mt) {
#pragma unroll
    for (int r = 0; r < 4; ++r) {
      float v = acc[mt][r] + bi[r];
      size_t idx = ((size_t)t * NG + n0 + nl + r) * 64 + mt * 16 + cc;
      if (XP32) ((float*)XPv)[idx] = v;
      else ((unsigned short*)XPv)[idx] = f2bf(v);
    }
  }
}

// ---------------- Phase B: persistent recurrence, tagged-data mailbox ----------------
// grid = 64: blk = bid>>4 (16 batches), slice = bid&15 (32 dims).
// R6 transport (single-hop tagged u64 words, exact-tag accept, parity-2, no fences) with:
//  - xp one-step register pipeline: xp(t+1) issued AFTER poll-t success; handed off
//    xp_nxt->xp_cur right after the next poll's vmcnt(0)+sched_barrier (drained => safe).
//    Poll rounds never wait on HBM; pointwise never waits on xp.
//  - missing-only retries: re-issue only stale producer chunks (wave-union mask).
//  - hl parity double-buffer: one barrier/step, race-free; ys/hT/cT direct from regs.
template <int XP32>
__global__ __launch_bounds__(256, 1) void lstm_rec(const unsigned short* __restrict__ Whh,
                                                   const void* __restrict__ XPv,
                                                   const float* __restrict__ bhh,
                                                   const float* __restrict__ h0,
                                                   const float* __restrict__ c0,
                                                   unsigned long long* __restrict__ mbox,
                                                   float* __restrict__ out) {
  __shared__ unsigned short hl[2][16 * 512];  // parity-buffered h block, XOR-swizzled (2x16KB)

  const int tid = threadIdx.x;
  const int lane = tid & 63, wid = tid >> 6;
  const int g = lane >> 4, cc = lane & 15;
  const int blk = blockIdx.x >> 4, slice = blockIdx.x & 15;
  const int b0 = blk * 16, d0 = slice * 32;

  // ---- publish our slice of h0 (tag=1) into parity-0 mailbox, ASAP (1 word/thread)
  {
    const int lp = tid >> 4, b = tid & 15;  // local pair, batch row
    const int d = d0 + lp * 2;
    const float* hp = h0 + (size_t)(b0 + b) * KD + d;
    unsigned d32 = (unsigned)f2bf(hp[0]) | ((unsigned)f2bf(hp[1]) << 16);
    __hip_atomic_store(mbox + (size_t)blk * MB_BLK_WORDS + ((d0 >> 1) + lp) * 16 + b,
                       (1ull << 32) | (unsigned long long)d32, __ATOMIC_RELAXED,
                       __HIP_MEMORY_SCOPE_AGENT);
  }

  // ---- preload W_hh slice into registers: 2 tiles x 16 k-steps of bf16x8
  bfrag w[2][16];
#pragma unroll
  for (int j = 0; j < 2; ++j) {
    const int tt = wid * 2 + j;
    const int r = tt * 16 + cc;  // A-operand row = lane&15
    const size_t n = (size_t)(r & 3) * KD + d0 + (r >> 2);
#pragma unroll
    for (int ks = 0; ks < 16; ++ks)
      w[j][ks] = *(const bfrag*)(Whh + n * KD + ks * 32 + g * 8);
  }
  float bh[2][4], creg[2];
#pragma unroll
  for (int j = 0; j < 2; ++j) {
    const int d = d0 + (wid * 2 + j) * 4 + g;
#pragma unroll
    for (int r = 0; r < 4; ++r) bh[j][r] = bhh[r * KD + d];
    creg[j] = c0[(b0 + cc) * KD + d];
  }

  unsigned long long q0, q1, q2, q3, q4, q5, q6, q7, q8, q9, q10, q11, q12, q13, q14, q15;
  unsigned xp_cur[2][4], xp_nxt[2][4];

  auto xp_issue = [&](unsigned(&dst)[2][4], int tt) {
#pragma unroll
    for (int j = 0; j < 2; ++j) {
      const int d = d0 + (wid * 2 + j) * 4 + g;
#pragma unroll
      for (int r = 0; r < 4; ++r) {
        const size_t idx = ((size_t)tt * NG + r * KD + d) * 64 + b0 + cc;
        if constexpr (XP32) {
          const float* p = (const float*)XPv + idx;
          asm volatile("global_load_dword %0, %1, off" : "=v"(dst[j][r]) : "v"(p) : "memory");
        } else {
          const unsigned short* p = (const unsigned short*)XPv + idx;
          asm volatile("global_load_ushort %0, %1, off" : "=v"(dst[j][r]) : "v"(p) : "memory");
        }
      }
    }
  };

#define PISSUE(MB, r)                                                       \
  asm volatile("global_load_dwordx2 %0, %1, %2 sc1"                         \
               : "=v"(q##r)                                                 \
               : "v"((unsigned)(tid * 8 + (r) * 2048)), "s"(MB) : "memory")
#define PISSUE_ALL(MB)                                                      \
  do {                                                                      \
    PISSUE(MB, 0); PISSUE(MB, 1); PISSUE(MB, 2); PISSUE(MB, 3);             \
    PISSUE(MB, 4); PISSUE(MB, 5); PISSUE(MB, 6); PISSUE(MB, 7);             \
    PISSUE(MB, 8); PISSUE(MB, 9); PISSUE(MB, 10); PISSUE(MB, 11);           \
    PISSUE(MB, 12); PISSUE(MB, 13); PISSUE(MB, 14); PISSUE(MB, 15);         \
  } while (0)
#define PMSK1(ms, tg, r) ms |= ((unsigned)(q##r >> 32) != (tg)) ? (1u << (r)) : 0u;
#define PMSK_ALL(ms, tg)                                                    \
  do {                                                                      \
    ms = 0u;                                                                \
    PMSK1(ms, tg, 0) PMSK1(ms, tg, 1) PMSK1(ms, tg, 2) PMSK1(ms, tg, 3)     \
    PMSK1(ms, tg, 4) PMSK1(ms, tg, 5) PMSK1(ms, tg, 6) PMSK1(ms, tg, 7)     \
    PMSK1(ms, tg, 8) PMSK1(ms, tg, 9) PMSK1(ms, tg, 10) PMSK1(ms, tg, 11)   \
    PMSK1(ms, tg, 12) PMSK1(ms, tg, 13) PMSK1(ms, tg, 14) PMSK1(ms, tg, 15) \
  } while (0)
#define PRET1(ms, MB, r) if (__any((ms) & (1u << (r)))) PISSUE(MB, r);
#define PRET_ALL(ms, MB)                                                    \
  do {                                                                      \
    PRET1(ms, MB, 0) PRET1(ms, MB, 1) PRET1(ms, MB, 2) PRET1(ms, MB, 3)     \
    PRET1(ms, MB, 4) PRET1(ms, MB, 5) PRET1(ms, MB, 6) PRET1(ms, MB, 7)     \
    PRET1(ms, MB, 8) PRET1(ms, MB, 9) PRET1(ms, MB, 10) PRET1(ms, MB, 11)   \
    PRET1(ms, MB, 12) PRET1(ms, MB, 13) PRET1(ms, MB, 14) PRET1(ms, MB, 15) \
  } while (0)

  // prologue: xp loads for t=0 (drained by the first poll's vmcnt(0))
  xp_issue(xp_nxt, 0);

  for (int t = 0; t < NT; ++t) {
    const int par = t & 1;
    const unsigned long long* mbr =
        mbox + (size_t)par * MB_PAR_WORDS + (size_t)blk * MB_BLK_WORDS;
    const unsigned tg = (unsigned)(t + 1);
    // ---- poll round 1: issue all 16 chunks, single drain
    PISSUE_ALL(mbr);
    asm volatile("s_waitcnt vmcnt(0)" ::: "memory");
    __builtin_amdgcn_sched_barrier(0);
    // xp hand-off: xp_nxt (issued last step) is drained by the wait above
#pragma unroll
    for (int j = 0; j < 2; ++j)
#pragma unroll
      for (int r = 0; r < 4; ++r) xp_cur[j][r] = xp_nxt[j][r];
    unsigned ms;
    PMSK_ALL(ms, tg);
    // ---- retries: re-issue ONLY the missing producer chunks
    while (__any(ms != 0u)) {
      PRET_ALL(ms, mbr);
      asm volatile("s_waitcnt vmcnt(0)" ::: "memory");
      __builtin_amdgcn_sched_barrier(0);
      PMSK_ALL(ms, tg);
    }
    // ---- issue next step's xp loads (complete long before next poll's drain)
    xp_issue(xp_nxt, (t + 1 < NT) ? t + 1 : t);
    // ---- unpack into swizzled LDS parity buffer
    {
      char* hlb = (char*)&hl[par][0];
      const int b = tid & 15, pq = tid >> 4;
      const int bb = b * 1024, bx = (b & 7) << 4;
#define PUNP(r) *(unsigned*)(hlb + bb + ((((r)*16 + pq) * 4) ^ bx)) = (unsigned)q##r;
      PUNP(0) PUNP(1) PUNP(2) PUNP(3) PUNP(4) PUNP(5) PUNP(6) PUNP(7)
      PUNP(8) PUNP(9) PUNP(10) PUNP(11) PUNP(12) PUNP(13) PUNP(14) PUNP(15)
#undef PUNP
    }
    __syncthreads();
    // ---- gates = W_slice @ h^T (4 accumulators, chains of 8)
    const char* hrb = (const char*)&hl[par][0] + cc * 1024;
    const int cx = (cc & 7) << 4;
    f32x4 p00 = {0.f, 0.f, 0.f, 0.f}, p01 = {0.f, 0.f, 0.f, 0.f};
    f32x4 p10 = {0.f, 0.f, 0.f, 0.f}, p11 = {0.f, 0.f, 0.f, 0.f};
#pragma unroll
    for (int ks = 0; ks < 8; ++ks) {
      const int off = ks * 64 + g * 16;
      bfrag hb = *(const bfrag*)(hrb + (off ^ cx));
      p00 = __builtin_amdgcn_mfma_f32_16x16x32_bf16(w[0][ks], hb, p00, 0, 0, 0);
      p10 = __builtin_amdgcn_mfma_f32_16x16x32_bf16(w[1][ks], hb, p10, 0, 0, 0);
    }
#pragma unroll
    for (int ks = 8; ks < 16; ++ks) {
      const int off = ks * 64 + g * 16;
      bfrag hb = *(const bfrag*)(hrb + (off ^ cx));
      p01 = __builtin_amdgcn_mfma_f32_16x16x32_bf16(w[0][ks], hb, p01, 0, 0, 0);
      p11 = __builtin_amdgcn_mfma_f32_16x16x32_bf16(w[1][ks], hb, p11, 0, 0, 0);
    }
    const f32x4 acc0 = p00 + p01, acc1 = p10 + p11;
    // ---- pointwise (xp_cur already in regs; no vmem wait)
    float hnv[2];
#pragma unroll
    for (int j = 0; j < 2; ++j) {
      const f32x4 a = j ? acc1 : acc0;
      float x0, x1, x2, x3;
      if constexpr (XP32) {
        x0 = __uint_as_float(xp_cur[j][0]); x1 = __uint_as_float(xp_cur[j][1]);
        x2 = __uint_as_float(xp_cur[j][2]); x3 = __uint_as_float(xp_cur[j][3]);
      } else {
        x0 = bf2f((unsigned short)xp_cur[j][0]); x1 = bf2f((unsigned short)xp_cur[j][1]);
        x2 = bf2f((unsigned short)xp_cur[j][2]); x3 = bf2f((unsigned short)xp_cur[j][3]);
      }
      float gi = a[0] + x0 + bh[j][0];
      float gf = a[1] + x1 + bh[j][1];
      float gg = a[2] + x2 + bh[j][2];
      float go = a[3] + x3 + bh[j][3];
      float cn = sigm(gf) * creg[j] + sigm(gi) * tanh_f(gg);
      creg[j] = cn;
      hnv[j] = sigm(go) * tanh_f(cn);
    }
    // ---- single-hop publish: pair dims via shfl, store (tag|bf16x2) words NOW; no drain
    {
      unsigned long long* mbw =
          mbox + (size_t)((t + 1) & 1) * MB_PAR_WORDS + (size_t)blk * MB_BLK_WORDS;
      const unsigned long long tagn = (unsigned long long)(unsigned)(t + 2) << 32;
      const float o0 = __shfl_xor(hnv[0], 16);
      const float o1 = __shfl_xor(hnv[1], 16);
      if (!(g & 1)) {
        const unsigned w0 = (unsigned)f2bf(hnv[0]) | ((unsigned)f2bf(o0) << 16);
        const unsigned w1 = (unsigned)f2bf(hnv[1]) | ((unsigned)f2bf(o1) << 16);
        const int p0 = (d0 >> 1) + wid * 4 + (g >> 1);
        const int p1 = p0 + 2;
        __hip_atomic_store(mbw + p0 * 16 + cc, tagn | (unsigned long long)w0,
                           __ATOMIC_RELAXED, __HIP_MEMORY_SCOPE_AGENT);
        __hip_atomic_store(mbw + p1 * 16 + cc, tagn | (unsigned long long)w1,
                           __ATOMIC_RELAXED, __HIP_MEMORY_SCOPE_AGENT);
      }
    }
    // ---- direct output stores from registers (fire-and-forget)
    {
      float* yb = out + (size_t)t * NB * KD + (size_t)(b0 + cc) * KD + d0 + wid * 8 + g;
      yb[0] = hnv[0];
      yb[4] = hnv[1];
      if (t == NT - 1) {
        float* hb = out + HT_OFF + (size_t)(b0 + cc) * KD + d0 + wid * 8 + g;
        hb[0] = hnv[0];
        hb[4] = hnv[1];
        float* cb = out + CT_OFF + (size_t)(b0 + cc) * KD + d0 + wid * 8 + g;
        cb[0] = creg[0];
        cb[4] = creg[1];
      }
    }
  }
#undef PISSUE
#undef PISSUE_ALL
#undef PMSK1
#undef PMSK_ALL
#undef PRET1
#undef PRET_ALL
}

extern "C" void kernel_launch(void* const* d_in, const int* in_sizes, int n_in,
                              void* d_out, int out_size, void* d_ws, size_t ws_size,
                              hipStream_t stream) {
  const float* x = (const float*)d_in[0];
  const float* h0 = (const float*)d_in[1];
  const float* c0 = (const float*)d_in[2];
  const float* Wih = (const float*)d_in[3];
  const float* Whh = (const float*)d_in[4];
  const float* bih = (const float*)d_in[5];
  const float* bhh = (const float*)d_in[6];
  float* out = (float*)d_out;
  char* ws = (char*)d_ws;

  unsigned long long* mbox = (unsigned long long*)ws;                      // 256KB
  unsigned short* WhhB = (unsigned short*)(ws + MB_BYTES);                 // 2MB
  unsigned short* WihB = (unsigned short*)(ws + MB_BYTES + 2097152);       // 2MB
  unsigned short* XB = (unsigned short*)(ws + MB_BYTES + 2 * 2097152);     // 32MB
  const size_t xp_off = MB_BYTES + 2ull * 2097152 + 33554432;
  void* XP = (void*)(ws + xp_off);
  const bool xp32 = ws_size >= xp_off + (size_t)NT * NG * 64 * 4;

  hipMemsetAsync(ws, 0, MB_BYTES, stream);  // reset mailbox tags (poison/replay safe)

  const int nx8 = NT * NB * KD / 8;
  const int nw8 = NG * KD / 8;
  cvt_bf16<<<dim3(nx8 / 256), 256, 0, stream>>>(x, XB, nx8);
  cvt_bf16<<<dim3(nw8 / 256), 256, 0, stream>>>(Wih, WihB, nw8);
  cvt_bf16<<<dim3(nw8 / 256), 256, 0, stream>>>(Whh, WhhB, nw8);

  if (xp32) {
    xproj_gemm<1><<<dim3(NG / 64, NT), 256, 0, stream>>>(WihB, XB, bih, XP);
    lstm_rec<1><<<dim3(GB * GH), 256, 0, stream>>>(WhhB, XP, bhh, h0, c0, mbox, out);
  } else {
    xproj_gemm<0><<<dim3(NG / 64, NT), 256, 0, stream>>>(WihB, XB, bih, XP);
    lstm_rec<0><<<dim3(GB * GH), 256, 0, stream>>>(WhhB, XP, bhh, h0, c0, mbox, out);
  }
}